// Round 10
// baseline (144.566 us; speedup 1.0000x reference)
//
#include <hip/hip_runtime.h>

// ISTSimulator: 131072 independent scan chains (B=65536, V=2), L=200 steps.
// One thread per chain. Outputs staged per-wave in LDS in 40-step chunks
// (stride-65 padding), then flushed as coalesced nontemporal float4 stores
// (160B runs per chain). Low VGPR, no __syncthreads (wave-private LDS).
// Lean per-step body: incremental sigmoid-arg accumulator (no cvt/fma),
// v_med3 clamp, raw v_log/v_exp/v_rcp trans ops.

#if __has_builtin(__builtin_amdgcn_exp2f)
#define FAST_EXP2(x) __builtin_amdgcn_exp2f(x)
#else
#define FAST_EXP2(x) exp2f(x)
#endif
#if __has_builtin(__builtin_amdgcn_logf)
#define FAST_LOG2(x) __builtin_amdgcn_logf(x)  // v_log_f32 = log2(x)
#else
#define FAST_LOG2(x) log2f(x)
#endif
#if __has_builtin(__builtin_amdgcn_fmed3f)
#define CLAMP01(x) __builtin_amdgcn_fmed3f((x), 0.0f, 1.0f)  // v_med3_f32
#else
#define CLAMP01(x) fminf(fmaxf((x), 0.0f), 1.0f)
#endif

namespace {
constexpr int kL = 200;
constexpr int kChunk = 40;               // steps per staged chunk (5 chunks)
constexpr int kNChunk = kL / kChunk;     // 5
constexpr int kS = 65;                   // LDS row stride in dwords (padded)
constexpr float kEps = 1e-12f;
constexpr float kLog2e = 1.44269504088896340736f;
typedef float v4f __attribute__((ext_vector_type(4)));  // native vec for nt-store
}  // namespace

__global__ __launch_bounds__(256) void ist_sim_kernel(
    const float* __restrict__ p, float* __restrict__ out) {
  // 4 waves * 40 steps * 65 dwords = 41.6 KB
  __shared__ float lds[4 * kChunk * kS];

  const int t = threadIdx.x;
  const int lane = t & 63;
  const int wave = t >> 6;
  float* wlds = lds + wave * kChunk * kS;

  const int tid = blockIdx.x * 256 + t;  // chain id = b*2 + v

  // params: [lam_raw, beta_raw, k_d, mu, k_f, n_c, w_t] at p[tid*7 + k]
  const float* q = p + tid * 7;
  const float lam  = 0.001f * fmaxf(q[0], 0.0f);
  const float beta = fmaf(10.0f, fmaxf(q[1], 0.0f), 1.0f);
  const float kd = q[2];
  const float mu = q[3];
  const float kf = q[4];
  const float nc = q[5];
  const float wt = q[6];

  // sigmoid arg in log2 domain: x2(n) = ((n - nc)/wt) * log2(e),
  // maintained incrementally: x2 starts at -nc*a2, += a2 per step.
  const float a2 = __builtin_amdgcn_rcpf(wt) * kLog2e;
  float x2 = -nc * a2;

  float D = 0.0f;
  float F = kEps;

  // global base for this wave's 64-chain group (dword units)
  float* gbase =
      out + ((size_t)blockIdx.x * 256 + (size_t)wave * 64) * kL;

  for (int ch = 0; ch < kNChunk; ++ch) {
#pragma unroll
    for (int i = 0; i < kChunk; ++i) {
      // D += lam * (1-D)^beta, clipped. (1.0f - 1e-12f == 1.0f in f32, same
      // as the jax reference's weak-typed clip constant.)
      const float om = fmaxf(1.0f - D, kEps);
      D = fminf(fmaf(lam, FAST_EXP2(beta * FAST_LOG2(om)), D), 1.0f);

      // g = sigmoid(x) = 1 / (1 + 2^(-x2)); neg folds into v_exp src mod
      const float g = __builtin_amdgcn_rcpf(1.0f + FAST_EXP2(-x2));
      x2 += a2;

      // F = clip((1 + mu*g)*F + eps*g, 0, 1)  -> v_med3_f32 clamp
      float v = fmaf(mu * g, F, F);
      v = fmaf(kEps, g, v);
      F = CLAMP01(v);

      // stage: step i of this lane's chain. bank = (i + lane) % 32 -> 2-way.
      wlds[i * kS + lane] = fmaf(kd, D, kf * F);
    }

    // Wave-local transposed flush: 64 chains x 10 float4 (160B per chain,
    // lane-consecutive within a chain -> coalesced full-line coverage).
    // Nontemporal: output is never re-read; keep it out of L2's way.
#pragma unroll
    for (int it = 0; it < 10; ++it) {
      const int f = it * 64 + lane;   // float4 index within the wave's flush
      const int c = f / 10;           // chain within the 64-group
      const int s = f - c * 10;       // float4 slot within the 40-step chunk
      v4f v;
      v.x = wlds[(4 * s + 0) * kS + c];
      v.y = wlds[(4 * s + 1) * kS + c];
      v.z = wlds[(4 * s + 2) * kS + c];
      v.w = wlds[(4 * s + 3) * kS + c];
      __builtin_nontemporal_store(
          v, reinterpret_cast<v4f*>(gbase + (size_t)c * kL + ch * kChunk +
                                    s * 4));
    }
  }
}

extern "C" void kernel_launch(void* const* d_in, const int* in_sizes, int n_in,
                              void* d_out, int out_size, void* d_ws,
                              size_t ws_size, hipStream_t stream) {
  const float* p = (const float*)d_in[0];
  float* out = (float*)d_out;
  const int total_chains = 65536 * 2;  // B * NUM_VARS
  ist_sim_kernel<<<total_chains / 256, 256, 0, stream>>>(p, out);
}

// Round 11
// 124.717 us; speedup vs baseline: 1.1591x; 1.1591x over previous
//
#include <hip/hip_runtime.h>

// ISTSimulator: 131072 independent scan chains (B=65536, V=2), L=200 steps.
// One thread per chain. Outputs staged per-wave in LDS in 40-step chunks
// (stride-65 padding), then flushed as coalesced float4 stores (160B runs per
// chain). Low VGPR, no __syncthreads (wave-private LDS regions).
// Lean per-step body: incremental sigmoid-arg accumulator, v_med3 clamp,
// raw v_log/v_exp/v_rcp trans ops. Plain (cached) stores: nt stores measured
// +14us in r10 -- L2 write-combining is the fast path for streaming writes.

#if __has_builtin(__builtin_amdgcn_exp2f)
#define FAST_EXP2(x) __builtin_amdgcn_exp2f(x)
#else
#define FAST_EXP2(x) exp2f(x)
#endif
#if __has_builtin(__builtin_amdgcn_logf)
#define FAST_LOG2(x) __builtin_amdgcn_logf(x)  // v_log_f32 = log2(x)
#else
#define FAST_LOG2(x) log2f(x)
#endif
#if __has_builtin(__builtin_amdgcn_fmed3f)
#define CLAMP01(x) __builtin_amdgcn_fmed3f((x), 0.0f, 1.0f)  // v_med3_f32
#else
#define CLAMP01(x) fminf(fmaxf((x), 0.0f), 1.0f)
#endif

namespace {
constexpr int kL = 200;
constexpr int kChunk = 40;               // steps per staged chunk (5 chunks)
constexpr int kNChunk = kL / kChunk;     // 5
constexpr int kS = 65;                   // LDS row stride in dwords (padded)
constexpr float kEps = 1e-12f;
constexpr float kLog2e = 1.44269504088896340736f;
}  // namespace

__global__ __launch_bounds__(256) void ist_sim_kernel(
    const float* __restrict__ p, float* __restrict__ out) {
  // 4 waves * 40 steps * 65 dwords = 41.6 KB
  __shared__ float lds[4 * kChunk * kS];

  const int t = threadIdx.x;
  const int lane = t & 63;
  const int wave = t >> 6;
  float* wlds = lds + wave * kChunk * kS;

  const int tid = blockIdx.x * 256 + t;  // chain id = b*2 + v

  // params: [lam_raw, beta_raw, k_d, mu, k_f, n_c, w_t] at p[tid*7 + k]
  const float* q = p + tid * 7;
  const float lam  = 0.001f * fmaxf(q[0], 0.0f);
  const float beta = fmaf(10.0f, fmaxf(q[1], 0.0f), 1.0f);
  const float kd = q[2];
  const float mu = q[3];
  const float kf = q[4];
  const float nc = q[5];
  const float wt = q[6];

  // sigmoid arg in log2 domain: x2(n) = ((n - nc)/wt) * log2(e),
  // maintained incrementally: x2 starts at -nc*a2, += a2 per step.
  const float a2 = __builtin_amdgcn_rcpf(wt) * kLog2e;
  float x2 = -nc * a2;

  float D = 0.0f;
  float F = kEps;

  // global base for this wave's 64-chain group (dword units)
  float* gbase =
      out + ((size_t)blockIdx.x * 256 + (size_t)wave * 64) * kL;

  for (int ch = 0; ch < kNChunk; ++ch) {
#pragma unroll
    for (int i = 0; i < kChunk; ++i) {
      // D += lam * (1-D)^beta, clipped. (1.0f - 1e-12f == 1.0f in f32, same
      // as the jax reference's weak-typed clip constant.)
      const float om = fmaxf(1.0f - D, kEps);
      D = fminf(fmaf(lam, FAST_EXP2(beta * FAST_LOG2(om)), D), 1.0f);

      // g = sigmoid(x) = 1 / (1 + 2^(-x2)); neg folds into v_exp src mod
      const float g = __builtin_amdgcn_rcpf(1.0f + FAST_EXP2(-x2));
      x2 += a2;

      // F = clip((1 + mu*g)*F + eps*g, 0, 1)  -> v_med3_f32 clamp
      float v = fmaf(mu * g, F, F);
      v = fmaf(kEps, g, v);
      F = CLAMP01(v);

      // stage: step i of this lane's chain. bank = (i + lane) % 32 -> 2-way.
      wlds[i * kS + lane] = fmaf(kd, D, kf * F);
    }

    // Wave-local transposed flush: 64 chains x 10 float4 (160B per chain,
    // lane-consecutive within a chain -> coalesced full-line coverage).
#pragma unroll
    for (int it = 0; it < 10; ++it) {
      const int f = it * 64 + lane;   // float4 index within the wave's flush
      const int c = f / 10;           // chain within the 64-group
      const int s = f - c * 10;       // float4 slot within the 40-step chunk
      float4 v;
      v.x = wlds[(4 * s + 0) * kS + c];
      v.y = wlds[(4 * s + 1) * kS + c];
      v.z = wlds[(4 * s + 2) * kS + c];
      v.w = wlds[(4 * s + 3) * kS + c];
      *reinterpret_cast<float4*>(gbase + (size_t)c * kL + ch * kChunk +
                                 s * 4) = v;
    }
  }
}

extern "C" void kernel_launch(void* const* d_in, const int* in_sizes, int n_in,
                              void* d_out, int out_size, void* d_ws,
                              size_t ws_size, hipStream_t stream) {
  const float* p = (const float*)d_in[0];
  float* out = (float*)d_out;
  const int total_chains = 65536 * 2;  // B * NUM_VARS
  ist_sim_kernel<<<total_chains / 256, 256, 0, stream>>>(p, out);
}